// Round 4
// baseline (118.344 us; speedup 1.0000x reference)
//
#include <hip/hip_runtime.h>
#include <stddef.h>

// B=1, H=16, S=4096, D=64, fp32.  out = (Q K^T) V == Q (K^T V)
// Stage 1 (A): P[h][c] = K_chunk^T V_chunk   (64x64 partials, 8x8/lane, wave-split s)
// Stage 2 (R): M[h] = sum_c P[h][c]
// Stage 3 (B): O[h] = Q[h] @ M[h]            (LDS-free: L1-broadcast Q and M)

#define SLEN 4096
#define DIM  64
#define NH   16
#define CH   32
#define RPC  128   // s-rows per stage-1 chunk (2 tiles of 64)

typedef float f4v __attribute__((ext_vector_type(4)));

// ---------------- Kernel A: partial M = K^T V over a 128-row chunk ----------------
// grid (32,16) x 256 thr. Each WAVE owns the full 64x64 partial over its 32 s-rows
// (8x8 acc per lane); cross-wave LDS reduce at end.  [~10us deduced in R3 — keep]
__global__ __launch_bounds__(256) void kvT_partial(const float* __restrict__ K,
                                                   const float* __restrict__ V,
                                                   float* __restrict__ P) {
    const int c = blockIdx.x, h = blockIdx.y, t = threadIdx.x;
    const int wave = t >> 6, lane = t & 63;
    const int i = lane >> 3, j = lane & 7;

    __shared__ float Ks[64][64];   // reused as reduce buffer M0
    __shared__ float Vs[64][64];   // reused as reduce buffer M1

    const f4v* K4 = (const f4v*)(K + ((size_t)h * SLEN + (size_t)c * RPC) * DIM);
    const f4v* V4 = (const f4v*)(V + ((size_t)h * SLEN + (size_t)c * RPC) * DIM);

    float acc[8][8];
    #pragma unroll
    for (int a = 0; a < 8; ++a) {
        #pragma unroll
        for (int b = 0; b < 8; ++b) acc[a][b] = 0.f;
    }

    f4v kst[4], vst[4];
    #pragma unroll
    for (int u = 0; u < 4; ++u) { kst[u] = K4[u * 256 + t]; vst[u] = V4[u * 256 + t]; }

    for (int tile = 0; tile < 2; ++tile) {
        __syncthreads();
        #pragma unroll
        for (int u = 0; u < 4; ++u) {
            int idx = u * 256 + t, row = idx >> 4, c4 = idx & 15;
            *(f4v*)&Ks[row][c4 * 4] = kst[u];
            *(f4v*)&Vs[row][c4 * 4] = vst[u];
        }
        __syncthreads();
        if (tile == 0) {
            #pragma unroll
            for (int u = 0; u < 4; ++u) {
                kst[u] = K4[1024 + u * 256 + t];
                vst[u] = V4[1024 + u * 256 + t];
            }
        }
        #pragma unroll
        for (int s0 = 0; s0 < 16; ++s0) {
            const int s = wave * 16 + s0;
            float kf[8], vf[8];
            *(f4v*)&kf[0] = *(const f4v*)&Ks[s][i * 8];
            *(f4v*)&kf[4] = *(const f4v*)&Ks[s][i * 8 + 4];
            *(f4v*)&vf[0] = *(const f4v*)&Vs[s][j * 8];
            *(f4v*)&vf[4] = *(const f4v*)&Vs[s][j * 8 + 4];
            #pragma unroll
            for (int a = 0; a < 8; ++a) {
                #pragma unroll
                for (int b = 0; b < 8; ++b)
                    acc[a][b] = fmaf(kf[a], vf[b], acc[a][b]);
            }
        }
    }

    __syncthreads();
    float* M0 = &Ks[0][0];
    float* M1 = &Vs[0][0];
    if (wave == 0 || wave == 2) {
        float* dst = (wave == 0) ? M0 : M1;
        #pragma unroll
        for (int r = 0; r < 8; ++r) {
            #pragma unroll
            for (int hh = 0; hh < 2; ++hh) {
                f4v x; x[0]=acc[r][hh*4]; x[1]=acc[r][hh*4+1]; x[2]=acc[r][hh*4+2]; x[3]=acc[r][hh*4+3];
                *(f4v*)&dst[(i * 8 + r) * 64 + j * 8 + hh * 4] = x;
            }
        }
    }
    __syncthreads();
    if (wave == 1 || wave == 3) {
        float* dst = (wave == 1) ? M0 : M1;
        #pragma unroll
        for (int r = 0; r < 8; ++r) {
            #pragma unroll
            for (int hh = 0; hh < 2; ++hh) {
                f4v x = *(f4v*)&dst[(i * 8 + r) * 64 + j * 8 + hh * 4];
                x[0]+=acc[r][hh*4]; x[1]+=acc[r][hh*4+1]; x[2]+=acc[r][hh*4+2]; x[3]+=acc[r][hh*4+3];
                *(f4v*)&dst[(i * 8 + r) * 64 + j * 8 + hh * 4] = x;
            }
        }
    }
    __syncthreads();
    float* Pc = P + ((size_t)h * CH + c) * (DIM * DIM);
    #pragma unroll
    for (int u = 0; u < 4; ++u) {
        int idx = u * 256 + t;
        f4v x = ((const f4v*)M0)[idx] + ((const f4v*)M1)[idx];
        ((f4v*)Pc)[idx] = x;
    }
}

// ---------------- Kernel R: M[h] = sum over 32 chunk-partials ----------------
__global__ __launch_bounds__(256) void reduceM(const float* __restrict__ P,
                                               float* __restrict__ M) {
    const int q = blockIdx.x, h = blockIdx.y, t = threadIdx.x;
    const int off = q * 256 + t;
    const f4v* Ph = (const f4v*)(P + (size_t)h * CH * DIM * DIM);
    f4v sum; sum[0]=0.f; sum[1]=0.f; sum[2]=0.f; sum[3]=0.f;
    #pragma unroll
    for (int c = 0; c < CH; ++c) sum += Ph[(size_t)c * (DIM * DIM / 4) + off];
    ((f4v*)(M + (size_t)h * DIM * DIM))[off] = sum;
}

// ---------------- Kernel B: O = Q @ M  (LDS-free) ----------------
// grid (64,16) x 256 thr. Thread (i=t>>4, j=t&15): rows i*4..+3, f4-col j of a
// 64x64 output chunk. Q rows: 16-lane L1 broadcast; M: 16 KB/head, L1-resident.
// No LDS, no barriers -> compiler pipelines freely; occupancy VGPR-bound only.
__global__ __launch_bounds__(256) void qm_kernel(const float* __restrict__ Q,
                                                 const float* __restrict__ Mm,
                                                 float* __restrict__ O) {
    const int chunk = blockIdx.x, h = blockIdx.y, t = threadIdx.x;
    const int i = t >> 4, j = t & 15;

    const f4v* Q4 = (const f4v*)(Q + ((size_t)h * SLEN + (size_t)chunk * 64 + i * 4) * DIM);
    const f4v* M4 = (const f4v*)(Mm + (size_t)h * DIM * DIM);

    float acc[4][4] = {{0.f,0.f,0.f,0.f},{0.f,0.f,0.f,0.f},
                       {0.f,0.f,0.f,0.f},{0.f,0.f,0.f,0.f}};

    #pragma unroll 4
    for (int d0 = 0; d0 < 16; ++d0) {           // depth in steps of 4
        f4v qf[4], mf[4];
        #pragma unroll
        for (int a = 0; a < 4; ++a)
            qf[a] = Q4[a * 16 + d0];            // row i*4+a, depth 4*d0.. (broadcast x16)
        #pragma unroll
        for (int cc = 0; cc < 4; ++cc)
            mf[cc] = M4[(d0 * 4 + cc) * 16 + j]; // row 4*d0+cc, f4-col j (coalesced 256B)
        #pragma unroll
        for (int a = 0; a < 4; ++a)
            #pragma unroll
            for (int cc = 0; cc < 4; ++cc)
                #pragma unroll
                for (int b = 0; b < 4; ++b)
                    acc[a][b] = fmaf(qf[a][cc], mf[cc][b], acc[a][b]);
    }

    f4v* O4 = (f4v*)(O + ((size_t)h * SLEN + (size_t)chunk * 64 + i * 4) * DIM);
    #pragma unroll
    for (int a = 0; a < 4; ++a) {
        f4v res;
        res[0] = acc[a][0]; res[1] = acc[a][1]; res[2] = acc[a][2]; res[3] = acc[a][3];
        O4[a * 16 + j] = res;
    }
}

extern "C" void kernel_launch(void* const* d_in, const int* in_sizes, int n_in,
                              void* d_out, int out_size, void* d_ws, size_t ws_size,
                              hipStream_t stream) {
    const float* q = (const float*)d_in[0];
    const float* k = (const float*)d_in[1];
    const float* v = (const float*)d_in[2];
    float* out = (float*)d_out;
    float* P = (float*)d_ws;                                  // 8 MiB
    float* M = P + (size_t)NH * CH * DIM * DIM;               // 256 KiB

    kvT_partial<<<dim3(CH, NH), 256, 0, stream>>>(k, v, P);
    reduceM<<<dim3(4, NH), 256, 0, stream>>>(P, M);
    qm_kernel<<<dim3(SLEN / 64, NH), 256, 0, stream>>>(q, M, out);
}